// Round 1
// baseline (1192.333 us; speedup 1.0000x reference)
//
#include <hip/hip_runtime.h>

#define N_NODES 50000
#define E_EDGES 800000
#define M_TOTAL (E_EDGES + N_NODES)
#define IN_DIM 128
#define HEADS 4
#define OUT_DIM 32
#define TOT 128
#define LN_EPS 1e-5f
#define NEG_SLOPE 0.2f

// order-preserving float->uint encoding for atomicMax
__device__ __forceinline__ unsigned enc_f(float f) {
    unsigned u = __float_as_uint(f);
    return (u & 0x80000000u) ? ~u : (u | 0x80000000u);
}
__device__ __forceinline__ float dec_f(unsigned e) {
    unsigned u = (e & 0x80000000u) ? (e & 0x7fffffffu) : ~e;
    return __uint_as_float(u);
}

// ---------------- 1. linear: xl = x@Wl + bl, xr = x@Wr + br ----------------
__global__ __launch_bounds__(128) void lin_kernel(
    const float* __restrict__ x,
    const float* __restrict__ Wl, const float* __restrict__ bl,
    const float* __restrict__ Wr, const float* __restrict__ br,
    float* __restrict__ xl, float* __restrict__ xr) {
    __shared__ float xs[IN_DIM];
    const int n = blockIdx.x;
    const int j = threadIdx.x;
    xs[j] = x[n * IN_DIM + j];
    __syncthreads();
    float al = bl[j], ar = br[j];
#pragma unroll 8
    for (int k = 0; k < IN_DIM; ++k) {
        const float xv = xs[k];
        al = fmaf(xv, Wl[k * TOT + j], al);
        ar = fmaf(xv, Wr[k * TOT + j], ar);
    }
    xl[n * TOT + j] = al;
    xr[n * TOT + j] = ar;
}

// ---------------- 2. per-edge score + per-dst max (wave per edge) ----------
__global__ __launch_bounds__(256) void score_kernel(
    const int* __restrict__ srcs, const int* __restrict__ dsts,
    const float* __restrict__ xl, const float* __restrict__ xr,
    const float* __restrict__ att,
    float* __restrict__ scores, unsigned* __restrict__ smax) {
    const int wave = (blockIdx.x * 256 + threadIdx.x) >> 6;
    const int lane = threadIdx.x & 63;
    if (wave >= M_TOTAL) return;
    int s, d;
    if (wave < E_EDGES) { s = srcs[wave]; d = dsts[wave]; }
    else                { s = d = wave - E_EDGES; }
    const float2 a = *(const float2*)&xl[s * TOT + 2 * lane];
    const float2 b = *(const float2*)&xr[d * TOT + 2 * lane];
    float m0 = a.x + b.x, m1 = a.y + b.y;
    m0 = m0 > 0.f ? m0 : NEG_SLOPE * m0;
    m1 = m1 > 0.f ? m1 : NEG_SLOPE * m1;
    const float2 at = *(const float2*)&att[2 * lane];
    float p = m0 * at.x + m1 * at.y;
    // dims [2*lane, 2*lane+1] belong to head lane>>4; reduce 16-lane groups
    p += __shfl_down(p, 8, 16);
    p += __shfl_down(p, 4, 16);
    p += __shfl_down(p, 2, 16);
    p += __shfl_down(p, 1, 16);
    if ((lane & 15) == 0) {
        const int h = lane >> 4;
        scores[wave * HEADS + h] = p;
        atomicMax(&smax[d * HEADS + h], enc_f(p));
    }
}

// ---------------- 3. exp + per-dst denom ----------------------------------
__global__ __launch_bounds__(256) void exp_kernel(
    const int* __restrict__ dsts,
    const unsigned* __restrict__ smax,
    float* __restrict__ scores, float* __restrict__ denom) {
    const int t = blockIdx.x * 256 + threadIdx.x;
    if (t >= M_TOTAL * HEADS) return;
    const int m = t >> 2, h = t & 3;
    const int d = (m < E_EDGES) ? dsts[m] : (m - E_EDGES);
    const float e = expf(scores[t] - dec_f(smax[d * HEADS + h]));
    scores[t] = e;  // overwrite score with exp value
    atomicAdd(&denom[d * HEADS + h], e);
}

// ---------------- 4. aggregate alpha * xl[src] into accum (atomics) -------
__global__ __launch_bounds__(256) void agg_kernel(
    const int* __restrict__ srcs, const int* __restrict__ dsts,
    const float* __restrict__ xl, const float* __restrict__ evals,
    const float* __restrict__ denom, float* __restrict__ accum) {
    const int wave = (blockIdx.x * 256 + threadIdx.x) >> 6;
    const int lane = threadIdx.x & 63;
    if (wave >= M_TOTAL) return;
    int s, d;
    if (wave < E_EDGES) { s = srcs[wave]; d = dsts[wave]; }
    else                { s = d = wave - E_EDGES; }
    const int h = lane >> 4;
    const float alpha = evals[wave * HEADS + h] / denom[d * HEADS + h];
    const float2 a = *(const float2*)&xl[s * TOT + 2 * lane];
    atomicAdd(&accum[d * TOT + 2 * lane],     alpha * a.x);
    atomicAdd(&accum[d * TOT + 2 * lane + 1], alpha * a.y);
}

// ---------------- 5. bias + residual + LayerNorm + ELU --------------------
__global__ __launch_bounds__(256) void ln_kernel(
    const float* __restrict__ accum, const float* __restrict__ x,
    const float* __restrict__ bias, const float* __restrict__ g,
    const float* __restrict__ bvec, float* __restrict__ out) {
    const int n = blockIdx.x * 4 + (threadIdx.x >> 6);
    const int lane = threadIdx.x & 63;
    if (n >= N_NODES) return;
    const float2 a  = *(const float2*)&accum[n * TOT + 2 * lane];
    const float2 xv = *(const float2*)&x[n * TOT + 2 * lane];
    const float2 bi = *(const float2*)&bias[2 * lane];
    const float v0 = a.x + bi.x + xv.x;
    const float v1 = a.y + bi.y + xv.y;
    float sum = v0 + v1, sq = v0 * v0 + v1 * v1;
#pragma unroll
    for (int off = 32; off >= 1; off >>= 1) {
        sum += __shfl_down(sum, off, 64);
        sq  += __shfl_down(sq,  off, 64);
    }
    sum = __shfl(sum, 0, 64);
    sq  = __shfl(sq, 0, 64);
    const float mu  = sum * (1.0f / TOT);
    const float var = sq * (1.0f / TOT) - mu * mu;
    const float inv = rsqrtf(var + LN_EPS);
    const float2 gg = *(const float2*)&g[2 * lane];
    const float2 bb = *(const float2*)&bvec[2 * lane];
    float y0 = (v0 - mu) * inv * gg.x + bb.x;
    float y1 = (v1 - mu) * inv * gg.y + bb.y;
    y0 = y0 > 0.f ? y0 : expf(y0) - 1.f;
    y1 = y1 > 0.f ? y1 : expf(y1) - 1.f;
    *(float2*)&out[n * TOT + 2 * lane] = make_float2(y0, y1);
}

extern "C" void kernel_launch(void* const* d_in, const int* in_sizes, int n_in,
                              void* d_out, int out_size, void* d_ws, size_t ws_size,
                              hipStream_t stream) {
    const float* x    = (const float*)d_in[0];
    const int*   ei   = (const int*)d_in[1];   // int32 (JAX x64 disabled)
    const float* Wl   = (const float*)d_in[2];
    const float* bl   = (const float*)d_in[3];
    const float* Wr   = (const float*)d_in[4];
    const float* br   = (const float*)d_in[5];
    const float* att  = (const float*)d_in[6];
    const float* bias = (const float*)d_in[7];
    const float* ln_g = (const float*)d_in[8];
    const float* ln_b = (const float*)d_in[9];
    const int* srcs = ei;
    const int* dsts = ei + E_EDGES;

    float* ws = (float*)d_ws;
    float*    xl     = ws;                               // N*128
    float*    xr     = xl + (size_t)N_NODES * TOT;       // N*128
    float*    scores = xr + (size_t)N_NODES * TOT;       // M*4
    float*    accum  = scores + (size_t)M_TOTAL * HEADS; // N*128 (zeroed)
    unsigned* smax   = (unsigned*)(accum + (size_t)N_NODES * TOT); // N*4 (zeroed)
    float*    denom  = (float*)(smax + (size_t)N_NODES * HEADS);   // N*4 (zeroed)

    // zero accum + smax + denom (contiguous)
    const size_t zero_bytes = ((size_t)N_NODES * TOT + (size_t)N_NODES * HEADS * 2) * sizeof(float);
    hipMemsetAsync(accum, 0, zero_bytes, stream);

    lin_kernel<<<N_NODES, 128, 0, stream>>>(x, Wl, bl, Wr, br, xl, xr);
    const int mblocks = (M_TOTAL + 3) / 4;
    score_kernel<<<mblocks, 256, 0, stream>>>(srcs, dsts, xl, xr, att, scores, smax);
    exp_kernel<<<(M_TOTAL * HEADS + 255) / 256, 256, 0, stream>>>(dsts, smax, scores, denom);
    agg_kernel<<<mblocks, 256, 0, stream>>>(srcs, dsts, xl, scores, denom, accum);
    ln_kernel<<<(N_NODES + 3) / 4, 256, 0, stream>>>(accum, x, bias, ln_g, ln_b, (float*)d_out);
}

// Round 2
// 537.454 us; speedup vs baseline: 2.2185x; 2.2185x over previous
//
#include <hip/hip_runtime.h>

#define N_NODES 50000
#define E_EDGES 800000
#define M_TOTAL (E_EDGES + N_NODES)
#define IN_DIM 128
#define HEADS 4
#define OUT_DIM 32
#define TOT 128
#define LN_EPS 1e-5f
#define NEG_SLOPE 0.2f

// ---------------- 1. linear: xl = x@Wl + bl, xr = x@Wr + br ----------------
__global__ __launch_bounds__(128) void lin_kernel(
    const float* __restrict__ x,
    const float* __restrict__ Wl, const float* __restrict__ bl,
    const float* __restrict__ Wr, const float* __restrict__ br,
    float* __restrict__ xl, float* __restrict__ xr) {
    __shared__ float xs[IN_DIM];
    const int n = blockIdx.x;
    const int j = threadIdx.x;
    xs[j] = x[n * IN_DIM + j];
    __syncthreads();
    float al = bl[j], ar = br[j];
#pragma unroll 8
    for (int k = 0; k < IN_DIM; ++k) {
        const float xv = xs[k];
        al = fmaf(xv, Wl[k * TOT + j], al);
        ar = fmaf(xv, Wr[k * TOT + j], ar);
    }
    xl[n * TOT + j] = al;
    xr[n * TOT + j] = ar;
}

// ---------------- 2. CSR build: histogram of dst ---------------------------
__global__ __launch_bounds__(256) void hist_kernel(
    const int* __restrict__ dsts, int* __restrict__ deg) {
    const int m = blockIdx.x * 256 + threadIdx.x;
    if (m >= M_TOTAL) return;
    const int d = (m < E_EDGES) ? dsts[m] : (m - E_EDGES);
    atomicAdd(&deg[d], 1);
}

// ---------------- 3. CSR build: exclusive scan (single block) --------------
__global__ __launch_bounds__(256) void scan_kernel(
    const int* __restrict__ deg, int* __restrict__ rowptr) {
    __shared__ int sums[256];
    const int t = threadIdx.x;
    const int chunk = (N_NODES + 255) / 256;
    const int beg = t * chunk;
    const int end = min(beg + chunk, N_NODES);
    int s = 0;
    for (int i = beg; i < end; ++i) s += deg[i];
    sums[t] = s;
    __syncthreads();
    // Hillis-Steele inclusive scan over 256 partials
    for (int off = 1; off < 256; off <<= 1) {
        int v = (t >= off) ? sums[t - off] : 0;
        __syncthreads();
        sums[t] += v;
        __syncthreads();
    }
    int run = (t == 0) ? 0 : sums[t - 1];
    for (int i = beg; i < end; ++i) { rowptr[i] = run; run += deg[i]; }
    if (t == 255) rowptr[N_NODES] = run;  // == M_TOTAL
}

// ---------------- 4. CSR build: scatter edges to dst-sorted order ----------
__global__ __launch_bounds__(256) void scatter_kernel(
    const int* __restrict__ srcs, const int* __restrict__ dsts,
    const int* __restrict__ rowptr, int* __restrict__ cursor,
    int* __restrict__ sorted_src) {
    const int m = blockIdx.x * 256 + threadIdx.x;
    if (m >= M_TOTAL) return;
    int s, d;
    if (m < E_EDGES) { s = srcs[m]; d = dsts[m]; }
    else             { s = d = m - E_EDGES; }
    const int pos = rowptr[d] + atomicAdd(&cursor[d], 1);
    sorted_src[pos] = s;
}

// ---------------- 5. fused GAT: score+softmax+agg+LN+ELU, wave per dst -----
__global__ __launch_bounds__(256) void gat_kernel(
    const int* __restrict__ rowptr, const int* __restrict__ sorted_src,
    const float* __restrict__ xl, const float* __restrict__ xr,
    const float* __restrict__ att, const float* __restrict__ x,
    const float* __restrict__ bias, const float* __restrict__ g,
    const float* __restrict__ bvec, float* __restrict__ out) {
    const int d = blockIdx.x * 4 + (threadIdx.x >> 6);
    const int lane = threadIdx.x & 63;
    if (d >= N_NODES) return;

    const float2 xrv = *(const float2*)&xr[d * TOT + 2 * lane];
    const float2 at  = *(const float2*)&att[2 * lane];
    const int beg = rowptr[d], end = rowptr[d + 1];

    float mx = -3.0e38f, l = 0.f, acc0 = 0.f, acc1 = 0.f;
    for (int base = beg; base < end; base += 64) {
        const int cnt = min(64, end - base);
        const int sv = (lane < cnt) ? sorted_src[base + lane] : 0;
        for (int j = 0; j < cnt; ++j) {
            const int s = __shfl(sv, j, 64);
            const float2 a = *(const float2*)&xl[s * TOT + 2 * lane];
            float m0 = a.x + xrv.x, m1 = a.y + xrv.y;
            m0 = m0 > 0.f ? m0 : NEG_SLOPE * m0;
            m1 = m1 > 0.f ? m1 : NEG_SLOPE * m1;
            // per-head (16-lane) dot-product reduction; all lanes get the sum
            float p = fmaf(m0, at.x, m1 * at.y);
            p += __shfl_xor(p, 1, 16);
            p += __shfl_xor(p, 2, 16);
            p += __shfl_xor(p, 4, 16);
            p += __shfl_xor(p, 8, 16);
            // online softmax update (per lane, within its head)
            const float nm    = fmaxf(mx, p);
            const float scale = __expf(mx - nm);
            const float el    = __expf(p - nm);
            l    = fmaf(l, scale, el);
            acc0 = fmaf(acc0, scale, el * a.x);
            acc1 = fmaf(acc1, scale, el * a.y);
            mx = nm;
        }
    }

    // epilogue: normalize, bias, residual, LayerNorm, ELU
    const float inv_l = 1.0f / l;
    const float2 xv = *(const float2*)&x[d * TOT + 2 * lane];
    const float2 bi = *(const float2*)&bias[2 * lane];
    const float v0 = fmaf(acc0, inv_l, bi.x + xv.x);
    const float v1 = fmaf(acc1, inv_l, bi.y + xv.y);
    float sum = v0 + v1, sq = v0 * v0 + v1 * v1;
#pragma unroll
    for (int off = 32; off >= 1; off >>= 1) {
        sum += __shfl_xor(sum, off, 64);
        sq  += __shfl_xor(sq,  off, 64);
    }
    const float mu  = sum * (1.0f / TOT);
    const float var = sq * (1.0f / TOT) - mu * mu;
    const float inv = rsqrtf(var + LN_EPS);
    const float2 gg = *(const float2*)&g[2 * lane];
    const float2 bb = *(const float2*)&bvec[2 * lane];
    float y0 = (v0 - mu) * inv * gg.x + bb.x;
    float y1 = (v1 - mu) * inv * gg.y + bb.y;
    y0 = y0 > 0.f ? y0 : __expf(y0) - 1.f;
    y1 = y1 > 0.f ? y1 : __expf(y1) - 1.f;
    *(float2*)&out[d * TOT + 2 * lane] = make_float2(y0, y1);
}

extern "C" void kernel_launch(void* const* d_in, const int* in_sizes, int n_in,
                              void* d_out, int out_size, void* d_ws, size_t ws_size,
                              hipStream_t stream) {
    const float* x    = (const float*)d_in[0];
    const int*   ei   = (const int*)d_in[1];
    const float* Wl   = (const float*)d_in[2];
    const float* bl   = (const float*)d_in[3];
    const float* Wr   = (const float*)d_in[4];
    const float* br   = (const float*)d_in[5];
    const float* att  = (const float*)d_in[6];
    const float* bias = (const float*)d_in[7];
    const float* ln_g = (const float*)d_in[8];
    const float* ln_b = (const float*)d_in[9];
    const int* srcs = ei;
    const int* dsts = ei + E_EDGES;

    float* ws = (float*)d_ws;
    float* xl = ws;                                  // N*128
    float* xr = xl + (size_t)N_NODES * TOT;          // N*128
    int*   deg        = (int*)(xr + (size_t)N_NODES * TOT); // N (zeroed)
    int*   cursor     = deg + N_NODES;                      // N (zeroed)
    int*   rowptr     = cursor + N_NODES;                   // N+1
    int*   sorted_src = rowptr + N_NODES + 1;               // M

    hipMemsetAsync(deg, 0, 2 * N_NODES * sizeof(int), stream);

    lin_kernel<<<N_NODES, 128, 0, stream>>>(x, Wl, bl, Wr, br, xl, xr);
    hist_kernel<<<(M_TOTAL + 255) / 256, 256, 0, stream>>>(dsts, deg);
    scan_kernel<<<1, 256, 0, stream>>>(deg, rowptr);
    scatter_kernel<<<(M_TOTAL + 255) / 256, 256, 0, stream>>>(srcs, dsts, rowptr, cursor, sorted_src);
    gat_kernel<<<(N_NODES + 3) / 4, 256, 0, stream>>>(rowptr, sorted_src, xl, xr, att, x,
                                                      bias, ln_g, ln_b, (float*)d_out);
}

// Round 3
// 374.866 us; speedup vs baseline: 3.1807x; 1.4337x over previous
//
#include <hip/hip_runtime.h>

#define N_NODES 50000
#define E_EDGES 800000
#define M_TOTAL (E_EDGES + N_NODES)
#define IN_DIM 128
#define HEADS 4
#define OUT_DIM 32
#define TOT 128
#define LN_EPS 1e-5f
#define NEG_SLOPE 0.2f

// ============ 1. tiled GEMM: [xl|xr] = x @ [Wl|Wr] + [bl|br] ==============
// C is 50000 x 256 (first 128 cols -> xl, last 128 -> xr).
// Tile: 64 m x 64 n per block, 4x4 per thread, K staged in 64-chunks.
#define GM 64
#define GN 64
#define KS 64

__global__ __launch_bounds__(256) void gemm_kernel(
    const float* __restrict__ x,
    const float* __restrict__ Wl, const float* __restrict__ bl,
    const float* __restrict__ Wr, const float* __restrict__ br,
    float* __restrict__ xl, float* __restrict__ xr) {
    __shared__ float As[KS][65];  // [k][m], pad 65 -> bank (k+m)%32
    __shared__ float Bs[KS][68];  // [k][n], pad 68 keeps float4 rows 16B-aligned

    const int t = threadIdx.x;
    const int m0 = blockIdx.x * GM;
    const int nb = blockIdx.y;            // 0..3
    const bool is_r = nb >= 2;
    const int j0 = (nb & 1) * GN;         // column offset within W (0 or 64)
    const float* __restrict__ W    = is_r ? Wr : Wl;
    const float* __restrict__ bvec = is_r ? br : bl;
    float* __restrict__ outp       = is_r ? xr : xl;

    const int tn = (t & 15) * 4;
    const int tm = (t >> 4) * 4;

    const float4 bv = *(const float4*)&bvec[j0 + tn];
    float acc[4][4];
#pragma unroll
    for (int i = 0; i < 4; ++i) {
        acc[i][0] = bv.x; acc[i][1] = bv.y; acc[i][2] = bv.z; acc[i][3] = bv.w;
    }

    for (int k0 = 0; k0 < IN_DIM; k0 += KS) {
        // stage A: x[m0+m][k0+4c+u] -> As[4c+u][m]; threads (mi=t>>4, c=t&15)
        {
            const int mi = t >> 4;        // 0..15
            const int c  = t & 15;        // 0..15
#pragma unroll
            for (int it = 0; it < 4; ++it) {
                const int m = mi + it * 16;
                int row = m0 + m; if (row >= N_NODES) row = N_NODES - 1;
                const float4 v = *(const float4*)&x[(size_t)row * IN_DIM + k0 + 4 * c];
                As[4*c+0][m] = v.x; As[4*c+1][m] = v.y;
                As[4*c+2][m] = v.z; As[4*c+3][m] = v.w;
            }
        }
        // stage B: W[k0+k][j0+4c] -> Bs[k][4c]
        {
            const int kk = t >> 4;        // 0..15
            const int c  = t & 15;
#pragma unroll
            for (int it = 0; it < 4; ++it) {
                const int k = kk + it * 16;
                const float4 v = *(const float4*)&W[(size_t)(k0 + k) * TOT + j0 + 4 * c];
                *(float4*)&Bs[k][4 * c] = v;
            }
        }
        __syncthreads();

#pragma unroll 8
        for (int k = 0; k < KS; ++k) {
            const float a0 = As[k][tm], a1 = As[k][tm+1], a2 = As[k][tm+2], a3 = As[k][tm+3];
            const float4 b = *(const float4*)&Bs[k][tn];
            acc[0][0] = fmaf(a0, b.x, acc[0][0]); acc[0][1] = fmaf(a0, b.y, acc[0][1]);
            acc[0][2] = fmaf(a0, b.z, acc[0][2]); acc[0][3] = fmaf(a0, b.w, acc[0][3]);
            acc[1][0] = fmaf(a1, b.x, acc[1][0]); acc[1][1] = fmaf(a1, b.y, acc[1][1]);
            acc[1][2] = fmaf(a1, b.z, acc[1][2]); acc[1][3] = fmaf(a1, b.w, acc[1][3]);
            acc[2][0] = fmaf(a2, b.x, acc[2][0]); acc[2][1] = fmaf(a2, b.y, acc[2][1]);
            acc[2][2] = fmaf(a2, b.z, acc[2][2]); acc[2][3] = fmaf(a2, b.w, acc[2][3]);
            acc[3][0] = fmaf(a3, b.x, acc[3][0]); acc[3][1] = fmaf(a3, b.y, acc[3][1]);
            acc[3][2] = fmaf(a3, b.z, acc[3][2]); acc[3][3] = fmaf(a3, b.w, acc[3][3]);
        }
        __syncthreads();
    }

#pragma unroll
    for (int i = 0; i < 4; ++i) {
        const int row = m0 + tm + i;
        if (row < N_NODES)
            *(float4*)&outp[(size_t)row * TOT + j0 + tn] =
                make_float4(acc[i][0], acc[i][1], acc[i][2], acc[i][3]);
    }
}

// ---------------- 2. CSR build: histogram of dst ---------------------------
__global__ __launch_bounds__(256) void hist_kernel(
    const int* __restrict__ dsts, int* __restrict__ deg) {
    const int m = blockIdx.x * 256 + threadIdx.x;
    if (m >= M_TOTAL) return;
    const int d = (m < E_EDGES) ? dsts[m] : (m - E_EDGES);
    atomicAdd(&deg[d], 1);
}

// ---------------- 3. CSR build: exclusive scan (single block) --------------
__global__ __launch_bounds__(256) void scan_kernel(
    const int* __restrict__ deg, int* __restrict__ rowptr) {
    __shared__ int sums[256];
    const int t = threadIdx.x;
    const int chunk = (N_NODES + 255) / 256;
    const int beg = t * chunk;
    const int end = min(beg + chunk, N_NODES);
    int s = 0;
    for (int i = beg; i < end; ++i) s += deg[i];
    sums[t] = s;
    __syncthreads();
    for (int off = 1; off < 256; off <<= 1) {
        int v = (t >= off) ? sums[t - off] : 0;
        __syncthreads();
        sums[t] += v;
        __syncthreads();
    }
    int run = (t == 0) ? 0 : sums[t - 1];
    for (int i = beg; i < end; ++i) { rowptr[i] = run; run += deg[i]; }
    if (t == 255) rowptr[N_NODES] = run;
}

// ---------------- 4. CSR build: scatter edges to dst-sorted order ----------
__global__ __launch_bounds__(256) void scatter_kernel(
    const int* __restrict__ srcs, const int* __restrict__ dsts,
    const int* __restrict__ rowptr, int* __restrict__ cursor,
    int* __restrict__ sorted_src) {
    const int m = blockIdx.x * 256 + threadIdx.x;
    if (m >= M_TOTAL) return;
    int s, d;
    if (m < E_EDGES) { s = srcs[m]; d = dsts[m]; }
    else             { s = d = m - E_EDGES; }
    const int pos = rowptr[d] + atomicAdd(&cursor[d], 1);
    sorted_src[pos] = s;
}

// ---------------- 5. fused GAT, wave per dst, 4-edge batched gathers -------
__device__ __forceinline__ float edge_score(float2 a, float2 xrv, float2 at) {
    float m0 = a.x + xrv.x, m1 = a.y + xrv.y;
    m0 = m0 > 0.f ? m0 : NEG_SLOPE * m0;
    m1 = m1 > 0.f ? m1 : NEG_SLOPE * m1;
    float p = fmaf(m0, at.x, m1 * at.y);
    p += __shfl_xor(p, 1, 16);
    p += __shfl_xor(p, 2, 16);
    p += __shfl_xor(p, 4, 16);
    p += __shfl_xor(p, 8, 16);
    return p;
}

__global__ __launch_bounds__(256) void gat_kernel(
    const int* __restrict__ rowptr, const int* __restrict__ sorted_src,
    const float* __restrict__ xl, const float* __restrict__ xr,
    const float* __restrict__ att, const float* __restrict__ x,
    const float* __restrict__ bias, const float* __restrict__ g,
    const float* __restrict__ bvec, float* __restrict__ out) {
    const int d = blockIdx.x * 4 + (threadIdx.x >> 6);
    const int lane = threadIdx.x & 63;
    if (d >= N_NODES) return;

    const float2 xrv = *(const float2*)&xr[d * TOT + 2 * lane];
    const float2 at  = *(const float2*)&att[2 * lane];
    const int beg = rowptr[d], end = rowptr[d + 1];

    float mx = -3.0e38f, l = 0.f, acc0 = 0.f, acc1 = 0.f;
    for (int base = beg; base < end; base += 64) {
        const int cnt = min(64, end - base);
        const int sv = (lane < cnt) ? sorted_src[base + lane] : 0;
        int j = 0;
        for (; j + 4 <= cnt; j += 4) {
            const int s0 = __shfl(sv, j,     64);
            const int s1 = __shfl(sv, j + 1, 64);
            const int s2 = __shfl(sv, j + 2, 64);
            const int s3 = __shfl(sv, j + 3, 64);
            const float2 a0 = *(const float2*)&xl[(size_t)s0 * TOT + 2 * lane];
            const float2 a1 = *(const float2*)&xl[(size_t)s1 * TOT + 2 * lane];
            const float2 a2 = *(const float2*)&xl[(size_t)s2 * TOT + 2 * lane];
            const float2 a3 = *(const float2*)&xl[(size_t)s3 * TOT + 2 * lane];
            const float p0 = edge_score(a0, xrv, at);
            const float p1 = edge_score(a1, xrv, at);
            const float p2 = edge_score(a2, xrv, at);
            const float p3 = edge_score(a3, xrv, at);
            const float pm = fmaxf(fmaxf(p0, p1), fmaxf(p2, p3));
            const float nm = fmaxf(mx, pm);
            const float scale = __expf(mx - nm);
            const float e0 = __expf(p0 - nm);
            const float e1 = __expf(p1 - nm);
            const float e2 = __expf(p2 - nm);
            const float e3 = __expf(p3 - nm);
            l    = fmaf(l,    scale, (e0 + e1) + (e2 + e3));
            acc0 = fmaf(acc0, scale, fmaf(e0, a0.x, fmaf(e1, a1.x, fmaf(e2, a2.x, e3 * a3.x))));
            acc1 = fmaf(acc1, scale, fmaf(e0, a0.y, fmaf(e1, a1.y, fmaf(e2, a2.y, e3 * a3.y))));
            mx = nm;
        }
        for (; j < cnt; ++j) {
            const int s = __shfl(sv, j, 64);
            const float2 a = *(const float2*)&xl[(size_t)s * TOT + 2 * lane];
            const float p = edge_score(a, xrv, at);
            const float nm = fmaxf(mx, p);
            const float scale = __expf(mx - nm);
            const float el = __expf(p - nm);
            l    = fmaf(l,    scale, el);
            acc0 = fmaf(acc0, scale, el * a.x);
            acc1 = fmaf(acc1, scale, el * a.y);
            mx = nm;
        }
    }

    const float inv_l = 1.0f / l;
    const float2 xv = *(const float2*)&x[d * TOT + 2 * lane];
    const float2 bi = *(const float2*)&bias[2 * lane];
    const float v0 = fmaf(acc0, inv_l, bi.x + xv.x);
    const float v1 = fmaf(acc1, inv_l, bi.y + xv.y);
    float sum = v0 + v1, sq = v0 * v0 + v1 * v1;
#pragma unroll
    for (int off = 32; off >= 1; off >>= 1) {
        sum += __shfl_xor(sum, off, 64);
        sq  += __shfl_xor(sq,  off, 64);
    }
    const float mu  = sum * (1.0f / TOT);
    const float var = sq * (1.0f / TOT) - mu * mu;
    const float inv = rsqrtf(var + LN_EPS);
    const float2 gg = *(const float2*)&g[2 * lane];
    const float2 bb = *(const float2*)&bvec[2 * lane];
    float y0 = (v0 - mu) * inv * gg.x + bb.x;
    float y1 = (v1 - mu) * inv * gg.y + bb.y;
    y0 = y0 > 0.f ? y0 : __expf(y0) - 1.f;
    y1 = y1 > 0.f ? y1 : __expf(y1) - 1.f;
    *(float2*)&out[d * TOT + 2 * lane] = make_float2(y0, y1);
}

extern "C" void kernel_launch(void* const* d_in, const int* in_sizes, int n_in,
                              void* d_out, int out_size, void* d_ws, size_t ws_size,
                              hipStream_t stream) {
    const float* x    = (const float*)d_in[0];
    const int*   ei   = (const int*)d_in[1];
    const float* Wl   = (const float*)d_in[2];
    const float* bl   = (const float*)d_in[3];
    const float* Wr   = (const float*)d_in[4];
    const float* br   = (const float*)d_in[5];
    const float* att  = (const float*)d_in[6];
    const float* bias = (const float*)d_in[7];
    const float* ln_g = (const float*)d_in[8];
    const float* ln_b = (const float*)d_in[9];
    const int* srcs = ei;
    const int* dsts = ei + E_EDGES;

    float* ws = (float*)d_ws;
    float* xl = ws;                                  // N*128
    float* xr = xl + (size_t)N_NODES * TOT;          // N*128
    int*   deg        = (int*)(xr + (size_t)N_NODES * TOT); // N (zeroed)
    int*   cursor     = deg + N_NODES;                      // N (zeroed)
    int*   rowptr     = cursor + N_NODES;                   // N+1
    int*   sorted_src = rowptr + N_NODES + 1;               // M

    hipMemsetAsync(deg, 0, 2 * N_NODES * sizeof(int), stream);

    hist_kernel<<<(M_TOTAL + 255) / 256, 256, 0, stream>>>(dsts, deg);
    scan_kernel<<<1, 256, 0, stream>>>(deg, rowptr);
    scatter_kernel<<<(M_TOTAL + 255) / 256, 256, 0, stream>>>(srcs, dsts, rowptr, cursor, sorted_src);

    dim3 ggrid((N_NODES + GM - 1) / GM, 4);
    gemm_kernel<<<ggrid, 256, 0, stream>>>(x, Wl, bl, Wr, br, xl, xr);

    gat_kernel<<<(N_NODES + 3) / 4, 256, 0, stream>>>(rowptr, sorted_src, xl, xr, att, x,
                                                      bias, ln_g, ln_b, (float*)d_out);
}

// Round 4
// 298.030 us; speedup vs baseline: 4.0007x; 1.2578x over previous
//
#include <hip/hip_runtime.h>

#define N_NODES 50000
#define E_EDGES 800000
#define M_TOTAL (E_EDGES + N_NODES)
#define IN_DIM 128
#define HEADS 4
#define OUT_DIM 32
#define TOT 128
#define LN_EPS 1e-5f
#define NEG_SLOPE 0.2f

#define SCAN_NBLK ((N_NODES + 255) / 256)   // 196

// ============ 1. tiled GEMM: [xl|xr] = x @ [Wl|Wr] + [bl|br] ==============
#define GM 64
#define GN 64
#define KS 64

__global__ __launch_bounds__(256) void gemm_kernel(
    const float* __restrict__ x,
    const float* __restrict__ Wl, const float* __restrict__ bl,
    const float* __restrict__ Wr, const float* __restrict__ br,
    float* __restrict__ xl, float* __restrict__ xr) {
    __shared__ float As[KS][65];
    __shared__ float Bs[KS][68];

    const int t = threadIdx.x;
    const int m0 = blockIdx.x * GM;
    const int nb = blockIdx.y;            // 0..3
    const bool is_r = nb >= 2;
    const int j0 = (nb & 1) * GN;
    const float* __restrict__ W    = is_r ? Wr : Wl;
    const float* __restrict__ bvec = is_r ? br : bl;
    float* __restrict__ outp       = is_r ? xr : xl;

    const int tn = (t & 15) * 4;
    const int tm = (t >> 4) * 4;

    const float4 bv = *(const float4*)&bvec[j0 + tn];
    float acc[4][4];
#pragma unroll
    for (int i = 0; i < 4; ++i) {
        acc[i][0] = bv.x; acc[i][1] = bv.y; acc[i][2] = bv.z; acc[i][3] = bv.w;
    }

    for (int k0 = 0; k0 < IN_DIM; k0 += KS) {
        {
            const int mi = t >> 4;
            const int c  = t & 15;
#pragma unroll
            for (int it = 0; it < 4; ++it) {
                const int m = mi + it * 16;
                int row = m0 + m; if (row >= N_NODES) row = N_NODES - 1;
                const float4 v = *(const float4*)&x[(size_t)row * IN_DIM + k0 + 4 * c];
                As[4*c+0][m] = v.x; As[4*c+1][m] = v.y;
                As[4*c+2][m] = v.z; As[4*c+3][m] = v.w;
            }
        }
        {
            const int kk = t >> 4;
            const int c  = t & 15;
#pragma unroll
            for (int it = 0; it < 4; ++it) {
                const int k = kk + it * 16;
                const float4 v = *(const float4*)&W[(size_t)(k0 + k) * TOT + j0 + 4 * c];
                *(float4*)&Bs[k][4 * c] = v;
            }
        }
        __syncthreads();

#pragma unroll 8
        for (int k = 0; k < KS; ++k) {
            const float a0 = As[k][tm], a1 = As[k][tm+1], a2 = As[k][tm+2], a3 = As[k][tm+3];
            const float4 b = *(const float4*)&Bs[k][tn];
            acc[0][0] = fmaf(a0, b.x, acc[0][0]); acc[0][1] = fmaf(a0, b.y, acc[0][1]);
            acc[0][2] = fmaf(a0, b.z, acc[0][2]); acc[0][3] = fmaf(a0, b.w, acc[0][3]);
            acc[1][0] = fmaf(a1, b.x, acc[1][0]); acc[1][1] = fmaf(a1, b.y, acc[1][1]);
            acc[1][2] = fmaf(a1, b.z, acc[1][2]); acc[1][3] = fmaf(a1, b.w, acc[1][3]);
            acc[2][0] = fmaf(a2, b.x, acc[2][0]); acc[2][1] = fmaf(a2, b.y, acc[2][1]);
            acc[2][2] = fmaf(a2, b.z, acc[2][2]); acc[2][3] = fmaf(a2, b.w, acc[2][3]);
            acc[3][0] = fmaf(a3, b.x, acc[3][0]); acc[3][1] = fmaf(a3, b.y, acc[3][1]);
            acc[3][2] = fmaf(a3, b.z, acc[3][2]); acc[3][3] = fmaf(a3, b.w, acc[3][3]);
        }
        __syncthreads();
    }

#pragma unroll
    for (int i = 0; i < 4; ++i) {
        const int row = m0 + tm + i;
        if (row < N_NODES)
            *(float4*)&outp[(size_t)row * TOT + j0 + tn] =
                make_float4(acc[i][0], acc[i][1], acc[i][2], acc[i][3]);
    }
}

// ---------------- 2. CSR build: histogram of dst ---------------------------
__global__ __launch_bounds__(256) void hist_kernel(
    const int* __restrict__ dsts, int* __restrict__ deg) {
    const int m = blockIdx.x * 256 + threadIdx.x;
    if (m >= M_TOTAL) return;
    const int d = (m < E_EDGES) ? dsts[m] : (m - E_EDGES);
    atomicAdd(&deg[d], 1);
}

// ---------------- 3a. scan phase 1: per-block inclusive scan ---------------
__global__ __launch_bounds__(256) void scan1_kernel(
    const int* __restrict__ deg, int* __restrict__ incl, int* __restrict__ blockSums) {
    __shared__ int sh[256];
    const int t = threadIdx.x;
    const int i = blockIdx.x * 256 + t;
    int v = (i < N_NODES) ? deg[i] : 0;
    sh[t] = v;
    __syncthreads();
#pragma unroll
    for (int off = 1; off < 256; off <<= 1) {
        int u = (t >= off) ? sh[t - off] : 0;
        __syncthreads();
        sh[t] += u;
        __syncthreads();
    }
    if (i < N_NODES) incl[i] = sh[t];
    if (t == 255) blockSums[blockIdx.x] = sh[255];
}

// ---------------- 3b. scan phase 2: exclusive scan of block sums -----------
__global__ __launch_bounds__(256) void scan2_kernel(
    const int* __restrict__ blockSums, int* __restrict__ blockOffs) {
    __shared__ int sh[256];
    const int t = threadIdx.x;
    sh[t] = (t < SCAN_NBLK) ? blockSums[t] : 0;
    __syncthreads();
#pragma unroll
    for (int off = 1; off < 256; off <<= 1) {
        int u = (t >= off) ? sh[t - off] : 0;
        __syncthreads();
        sh[t] += u;
        __syncthreads();
    }
    if (t < SCAN_NBLK) blockOffs[t] = (t == 0) ? 0 : sh[t - 1];
}

// ---------------- 3c. scan phase 3: finalize exclusive rowptr --------------
__global__ __launch_bounds__(256) void scan3_kernel(
    const int* __restrict__ deg, const int* __restrict__ blockOffs,
    int* __restrict__ rowptr /* holds incl from phase 1 */) {
    const int i = blockIdx.x * 256 + threadIdx.x;
    if (i < N_NODES)
        rowptr[i] = blockOffs[blockIdx.x] + rowptr[i] - deg[i];
    if (i == 0) rowptr[N_NODES] = M_TOTAL;
}

// ---------------- 4. CSR build: scatter edges to dst-sorted order ----------
__global__ __launch_bounds__(256) void scatter_kernel(
    const int* __restrict__ srcs, const int* __restrict__ dsts,
    const int* __restrict__ rowptr, int* __restrict__ cursor,
    int* __restrict__ sorted_src) {
    const int m = blockIdx.x * 256 + threadIdx.x;
    if (m >= M_TOTAL) return;
    int s, d;
    if (m < E_EDGES) { s = srcs[m]; d = dsts[m]; }
    else             { s = d = m - E_EDGES; }
    const int pos = rowptr[d] + atomicAdd(&cursor[d], 1);
    sorted_src[pos] = s;
}

// ---------------- 5. fused GAT, wave per dst, 4-edge batched gathers -------
__device__ __forceinline__ float edge_score(float2 a, float2 xrv, float2 at) {
    float m0 = a.x + xrv.x, m1 = a.y + xrv.y;
    m0 = m0 > 0.f ? m0 : NEG_SLOPE * m0;
    m1 = m1 > 0.f ? m1 : NEG_SLOPE * m1;
    float p = fmaf(m0, at.x, m1 * at.y);
    p += __shfl_xor(p, 1, 16);
    p += __shfl_xor(p, 2, 16);
    p += __shfl_xor(p, 4, 16);
    p += __shfl_xor(p, 8, 16);
    return p;
}

__global__ __launch_bounds__(256) void gat_kernel(
    const int* __restrict__ rowptr, const int* __restrict__ sorted_src,
    const float* __restrict__ xl, const float* __restrict__ xr,
    const float* __restrict__ att, const float* __restrict__ x,
    const float* __restrict__ bias, const float* __restrict__ g,
    const float* __restrict__ bvec, float* __restrict__ out) {
    const int d = blockIdx.x * 4 + (threadIdx.x >> 6);
    const int lane = threadIdx.x & 63;
    if (d >= N_NODES) return;

    const float2 xrv = *(const float2*)&xr[d * TOT + 2 * lane];
    const float2 at  = *(const float2*)&att[2 * lane];
    const int beg = rowptr[d], end = rowptr[d + 1];

    float mx = -3.0e38f, l = 0.f, acc0 = 0.f, acc1 = 0.f;
    for (int base = beg; base < end; base += 64) {
        const int cnt = min(64, end - base);
        const int sv = (lane < cnt) ? sorted_src[base + lane] : 0;
        int j = 0;
        for (; j + 4 <= cnt; j += 4) {
            const int s0 = __shfl(sv, j,     64);
            const int s1 = __shfl(sv, j + 1, 64);
            const int s2 = __shfl(sv, j + 2, 64);
            const int s3 = __shfl(sv, j + 3, 64);
            const float2 a0 = *(const float2*)&xl[(size_t)s0 * TOT + 2 * lane];
            const float2 a1 = *(const float2*)&xl[(size_t)s1 * TOT + 2 * lane];
            const float2 a2 = *(const float2*)&xl[(size_t)s2 * TOT + 2 * lane];
            const float2 a3 = *(const float2*)&xl[(size_t)s3 * TOT + 2 * lane];
            const float p0 = edge_score(a0, xrv, at);
            const float p1 = edge_score(a1, xrv, at);
            const float p2 = edge_score(a2, xrv, at);
            const float p3 = edge_score(a3, xrv, at);
            const float pm = fmaxf(fmaxf(p0, p1), fmaxf(p2, p3));
            const float nm = fmaxf(mx, pm);
            const float scale = __expf(mx - nm);
            const float e0 = __expf(p0 - nm);
            const float e1 = __expf(p1 - nm);
            const float e2 = __expf(p2 - nm);
            const float e3 = __expf(p3 - nm);
            l    = fmaf(l,    scale, (e0 + e1) + (e2 + e3));
            acc0 = fmaf(acc0, scale, fmaf(e0, a0.x, fmaf(e1, a1.x, fmaf(e2, a2.x, e3 * a3.x))));
            acc1 = fmaf(acc1, scale, fmaf(e0, a0.y, fmaf(e1, a1.y, fmaf(e2, a2.y, e3 * a3.y))));
            mx = nm;
        }
        for (; j < cnt; ++j) {
            const int s = __shfl(sv, j, 64);
            const float2 a = *(const float2*)&xl[(size_t)s * TOT + 2 * lane];
            const float p = edge_score(a, xrv, at);
            const float nm = fmaxf(mx, p);
            const float scale = __expf(mx - nm);
            const float el = __expf(p - nm);
            l    = fmaf(l,    scale, el);
            acc0 = fmaf(acc0, scale, el * a.x);
            acc1 = fmaf(acc1, scale, el * a.y);
            mx = nm;
        }
    }

    const float inv_l = 1.0f / l;
    const float2 xv = *(const float2*)&x[d * TOT + 2 * lane];
    const float2 bi = *(const float2*)&bias[2 * lane];
    const float v0 = fmaf(acc0, inv_l, bi.x + xv.x);
    const float v1 = fmaf(acc1, inv_l, bi.y + xv.y);
    float sum = v0 + v1, sq = v0 * v0 + v1 * v1;
#pragma unroll
    for (int off = 32; off >= 1; off >>= 1) {
        sum += __shfl_xor(sum, off, 64);
        sq  += __shfl_xor(sq,  off, 64);
    }
    const float mu  = sum * (1.0f / TOT);
    const float var = sq * (1.0f / TOT) - mu * mu;
    const float inv = rsqrtf(var + LN_EPS);
    const float2 gg = *(const float2*)&g[2 * lane];
    const float2 bb = *(const float2*)&bvec[2 * lane];
    float y0 = (v0 - mu) * inv * gg.x + bb.x;
    float y1 = (v1 - mu) * inv * gg.y + bb.y;
    y0 = y0 > 0.f ? y0 : __expf(y0) - 1.f;
    y1 = y1 > 0.f ? y1 : __expf(y1) - 1.f;
    *(float2*)&out[d * TOT + 2 * lane] = make_float2(y0, y1);
}

extern "C" void kernel_launch(void* const* d_in, const int* in_sizes, int n_in,
                              void* d_out, int out_size, void* d_ws, size_t ws_size,
                              hipStream_t stream) {
    const float* x    = (const float*)d_in[0];
    const int*   ei   = (const int*)d_in[1];
    const float* Wl   = (const float*)d_in[2];
    const float* bl   = (const float*)d_in[3];
    const float* Wr   = (const float*)d_in[4];
    const float* br   = (const float*)d_in[5];
    const float* att  = (const float*)d_in[6];
    const float* bias = (const float*)d_in[7];
    const float* ln_g = (const float*)d_in[8];
    const float* ln_b = (const float*)d_in[9];
    const int* srcs = ei;
    const int* dsts = ei + E_EDGES;

    float* ws = (float*)d_ws;
    float* xl = ws;                                  // N*128
    float* xr = xl + (size_t)N_NODES * TOT;          // N*128
    int*   deg        = (int*)(xr + (size_t)N_NODES * TOT); // N (zeroed)
    int*   cursor     = deg + N_NODES;                      // N (zeroed)
    int*   rowptr     = cursor + N_NODES;                   // N+1
    int*   sorted_src = rowptr + N_NODES + 1;               // M
    int*   blockSums  = sorted_src + M_TOTAL;               // SCAN_NBLK
    int*   blockOffs  = blockSums + SCAN_NBLK;              // SCAN_NBLK

    hipMemsetAsync(deg, 0, 2 * N_NODES * sizeof(int), stream);

    hist_kernel<<<(M_TOTAL + 255) / 256, 256, 0, stream>>>(dsts, deg);
    scan1_kernel<<<SCAN_NBLK, 256, 0, stream>>>(deg, rowptr, blockSums);
    scan2_kernel<<<1, 256, 0, stream>>>(blockSums, blockOffs);
    scan3_kernel<<<SCAN_NBLK, 256, 0, stream>>>(deg, blockOffs, rowptr);
    scatter_kernel<<<(M_TOTAL + 255) / 256, 256, 0, stream>>>(srcs, dsts, rowptr, cursor, sorted_src);

    dim3 ggrid((N_NODES + GM - 1) / GM, 4);
    gemm_kernel<<<ggrid, 256, 0, stream>>>(x, Wl, bl, Wr, br, xl, xr);

    gat_kernel<<<(N_NODES + 3) / 4, 256, 0, stream>>>(rowptr, sorted_src, xl, xr, att, x,
                                                      bias, ln_g, ln_b, (float*)d_out);
}